// Round 1
// baseline (419.023 us; speedup 1.0000x reference)
//
#include <hip/hip_runtime.h>
#include <math.h>

#define B_   2
#define S_   16384
#define C_   128
#define NH_  2
#define HD_  64
#define SK_  1024
#define IMW_ 128
#define EPS_ 1e-5f

// ---------------------------------------------------------------- transposes
__global__ void k_transpose128(const float* __restrict__ W, float* __restrict__ WT) {
    int idx = blockIdx.x * 256 + threadIdx.x;      // 16384
    int k = idx >> 7, j = idx & 127;
    WT[idx] = W[j * 128 + k];                      // WT[k][j] = W[j][k]
}

__global__ void k_wsr_transpose(const float* __restrict__ Wsr, float* __restrict__ WT) {
    int idx = blockIdx.x * 256 + threadIdx.x;      // 262144
    int co  = idx & 127;
    int ci  = (idx >> 7) & 127;
    int tap = idx >> 14;                           // 0..15 = ky*4+kx
    WT[idx] = Wsr[(co * 128 + ci) * 16 + tap];     // WT[tap][ci][co]
}

// fr_img/fi_img: mean over 4x4 position blocks of freqs_cis
__global__ void k_freq_avg(const float* __restrict__ fc,
                           float* __restrict__ frk, float* __restrict__ fik) {
    int idx = blockIdx.x * 256 + threadIdx.x;      // 32768 = 1024*32
    int c  = idx & 31;
    int kk = idx >> 5;
    int y = kk >> 5, x = kk & 31;
    float sr = 0.f, si = 0.f;
    #pragma unroll
    for (int i1 = 0; i1 < 4; ++i1)
        #pragma unroll
        for (int i3 = 0; i3 < 4; ++i3) {
            int s = (4 * y + i1) * IMW_ + 4 * x + i3;
            sr += fc[s * 64 + c * 2];
            si += fc[s * 64 + c * 2 + 1];
        }
    frk[idx] = sr * 0.0625f;
    fik[idx] = si * 0.0625f;
}

// ---------------------------------------------------------------- GEMM + RoPE
// out = X @ W^T + bias (rows = B*SEQP), optional RoPE.
// WT is k-major: WT[k][j] = W[j][k].
// ROPE_MODE: 0 = per-pos interleaved freqs_cis, 1 = frk/fik arrays, 2 = none
// OUTT: 0 -> out[bh][pos][64] ; 1 -> out[bh][dim][SEQP] (transposed)
template<int ROPE_MODE, int OUTT>
__global__ __launch_bounds__(256) void k_gemm_rope(
    const float* __restrict__ X, const float* __restrict__ WT,
    const float* __restrict__ bias, const float* __restrict__ fr,
    const float* __restrict__ fi, float* __restrict__ out, int SEQP)
{
    __shared__ __align__(16) float sX[32][132];
    __shared__ __align__(16) float sW[64][128];
    const int t = threadIdx.x;
    const int row0 = blockIdx.x * 32;
    #pragma unroll
    for (int i = 0; i < 4; ++i) {
        int f = t + i * 256;
        int r = f >> 5, k4 = f & 31;
        *(float4*)(&sX[r][k4 * 4]) =
            *(const float4*)(X + (size_t)(row0 + r) * 128 + k4 * 4);
    }
    const int rg = t >> 4, pg = t & 15;
    const int j0 = pg * 8;
    float acc[2][8];
    #pragma unroll
    for (int i = 0; i < 2; ++i)
        #pragma unroll
        for (int j = 0; j < 8; ++j) acc[i][j] = 0.f;

    for (int half = 0; half < 2; ++half) {
        __syncthreads();
        #pragma unroll
        for (int i = 0; i < 8; ++i) {
            int f = t + i * 256;
            int kk = f >> 5, j4 = f & 31;
            *(float4*)(&sW[kk][j4 * 4]) =
                *(const float4*)(WT + (size_t)(half * 64 + kk) * 128 + j4 * 4);
        }
        __syncthreads();
        #pragma unroll 4
        for (int k4 = 0; k4 < 16; ++k4) {
            float4 hv[2];
            #pragma unroll
            for (int i = 0; i < 2; ++i)
                hv[i] = *(const float4*)(&sX[rg + 16 * i][half * 64 + k4 * 4]);
            #pragma unroll
            for (int kk = 0; kk < 4; ++kk) {
                float4 w0 = *(const float4*)(&sW[k4 * 4 + kk][j0]);
                float4 w1 = *(const float4*)(&sW[k4 * 4 + kk][j0 + 4]);
                #pragma unroll
                for (int i = 0; i < 2; ++i) {
                    float hx = (&hv[i].x)[kk];
                    acc[i][0] += hx * w0.x; acc[i][1] += hx * w0.y;
                    acc[i][2] += hx * w0.z; acc[i][3] += hx * w0.w;
                    acc[i][4] += hx * w1.x; acc[i][5] += hx * w1.y;
                    acc[i][6] += hx * w1.z; acc[i][7] += hx * w1.w;
                }
            }
        }
    }

    const int h  = j0 >> 6;
    const int jl = j0 & 63;
    float bv[8];
    #pragma unroll
    for (int j = 0; j < 8; ++j) bv[j] = bias[j0 + j];
    #pragma unroll
    for (int i = 0; i < 2; ++i) {
        int row = row0 + rg + 16 * i;
        int b   = row / SEQP;
        int pos = row - b * SEQP;
        float o[8];
        if (ROPE_MODE == 2) {
            #pragma unroll
            for (int j = 0; j < 8; ++j) o[j] = acc[i][j] + bv[j];
        } else {
            #pragma unroll
            for (int p = 0; p < 4; ++p) {
                float xr = acc[i][2 * p]     + bv[2 * p];
                float xi = acc[i][2 * p + 1] + bv[2 * p + 1];
                int c = (jl >> 1) + p;
                float frv, fiv;
                if (ROPE_MODE == 0) {
                    frv = fr[(size_t)pos * 64 + c * 2];
                    fiv = fr[(size_t)pos * 64 + c * 2 + 1];
                } else {
                    frv = fr[(size_t)pos * 32 + c];
                    fiv = fi[(size_t)pos * 32 + c];
                }
                o[2 * p]     = xr * frv - xi * fiv;
                o[2 * p + 1] = xr * fiv + xi * frv;
            }
        }
        if (OUTT == 0) {
            float* dst = out + ((size_t)(b * NH_ + h) * SEQP + pos) * 64 + jl;
            *(float4*)(dst)     = make_float4(o[0], o[1], o[2], o[3]);
            *(float4*)(dst + 4) = make_float4(o[4], o[5], o[6], o[7]);
        } else {
            #pragma unroll
            for (int j = 0; j < 8; ++j)
                out[((size_t)(b * NH_ + h) * 64 + jl + j) * SEQP + pos] = o[j];
        }
    }
}

// ---------------------------------------------------------------- conv (4x4/s4 = patch GEMM), split-K
// partial[split][2048][128]; bias NOT added here (added once in LN).
__global__ __launch_bounds__(256) void k_conv(
    const float* __restrict__ hid, const float* __restrict__ WsrT,
    float* __restrict__ partial)
{
    __shared__ __align__(16) float sA[32][68];
    __shared__ __align__(16) float sB[64][128];
    const int t = threadIdx.x;
    const int split = blockIdx.x >> 6;        // 0..3 -> taps split*4 .. split*4+3
    const int by = blockIdx.x & 63;
    const int b = by >> 5, y = by & 31;
    const int rg = t >> 4, pg = t & 15;
    float acc[2][8];
    #pragma unroll
    for (int i = 0; i < 2; ++i)
        #pragma unroll
        for (int j = 0; j < 8; ++j) acc[i][j] = 0.f;

    for (int cc = 0; cc < 8; ++cc) {
        const int tap = split * 4 + (cc >> 1);
        const int ky = tap >> 2, kx = tap & 3;
        const int ci0 = (cc & 1) * 64;
        __syncthreads();
        #pragma unroll
        for (int i = 0; i < 2; ++i) {
            int f = t + i * 256;
            int pos = f >> 4, k4 = f & 15;
            int srow = (4 * y + ky) * IMW_ + 4 * pos + kx;
            *(float4*)(&sA[pos][k4 * 4]) =
                *(const float4*)(hid + ((size_t)b * S_ + srow) * 128 + ci0 + k4 * 4);
        }
        #pragma unroll
        for (int i = 0; i < 8; ++i) {
            int f = t + i * 256;
            int kk = f >> 5, j4 = f & 31;
            *(float4*)(&sB[kk][j4 * 4]) =
                *(const float4*)(WsrT + ((size_t)tap * 128 + ci0 + kk) * 128 + j4 * 4);
        }
        __syncthreads();
        #pragma unroll 4
        for (int kk = 0; kk < 64; ++kk) {
            float a0 = sA[rg][kk], a1 = sA[rg + 16][kk];
            float4 w0 = *(const float4*)(&sB[kk][pg * 8]);
            float4 w1 = *(const float4*)(&sB[kk][pg * 8 + 4]);
            acc[0][0] += a0 * w0.x; acc[0][1] += a0 * w0.y;
            acc[0][2] += a0 * w0.z; acc[0][3] += a0 * w0.w;
            acc[0][4] += a0 * w1.x; acc[0][5] += a0 * w1.y;
            acc[0][6] += a0 * w1.z; acc[0][7] += a0 * w1.w;
            acc[1][0] += a1 * w0.x; acc[1][1] += a1 * w0.y;
            acc[1][2] += a1 * w0.z; acc[1][3] += a1 * w0.w;
            acc[1][4] += a1 * w1.x; acc[1][5] += a1 * w1.y;
            acc[1][6] += a1 * w1.z; acc[1][7] += a1 * w1.w;
        }
    }
    #pragma unroll
    for (int i = 0; i < 2; ++i) {
        int pos = b * SK_ + y * 32 + rg + 16 * i;
        float* dst = partial + ((size_t)split * 2048 + pos) * 128 + pg * 8;
        *(float4*)(dst)     = make_float4(acc[i][0], acc[i][1], acc[i][2], acc[i][3]);
        *(float4*)(dst + 4) = make_float4(acc[i][4], acc[i][5], acc[i][6], acc[i][7]);
    }
}

// ---------------------------------------------------------------- LN (fuses split-K reduce + b_sr)
__global__ __launch_bounds__(256) void k_ln(
    const float* __restrict__ partial, const float* __restrict__ bsr,
    const float* __restrict__ g, const float* __restrict__ bb,
    float* __restrict__ XR)
{
    const int t = threadIdx.x;
    const int row = blockIdx.x * 4 + (t >> 6);
    const int lane = t & 63;
    float x0 = bsr[lane], x1 = bsr[64 + lane];
    #pragma unroll
    for (int s = 0; s < 4; ++s) {
        x0 += partial[((size_t)s * 2048 + row) * 128 + lane];
        x1 += partial[((size_t)s * 2048 + row) * 128 + 64 + lane];
    }
    float sum = x0 + x1;
    #pragma unroll
    for (int m = 1; m < 64; m <<= 1) sum += __shfl_xor(sum, m, 64);
    float mu = sum * (1.0f / 128.0f);
    float d0 = x0 - mu, d1 = x1 - mu;
    float vs = d0 * d0 + d1 * d1;
    #pragma unroll
    for (int m = 1; m < 64; m <<= 1) vs += __shfl_xor(vs, m, 64);
    float rstd = rsqrtf(vs * (1.0f / 128.0f) + EPS_);
    XR[(size_t)row * 128 + lane]      = d0 * rstd * g[lane]      + bb[lane];
    XR[(size_t)row * 128 + 64 + lane] = d1 * rstd * g[64 + lane] + bb[64 + lane];
}

// ---------------------------------------------------------------- flash attention (fp32)
// QT: [4][64][16384] (pre-scaled NOT: scaled here), KT: [4][64][1024], V: [4][1024][64]
__global__ __launch_bounds__(256) void k_attn(
    const float* __restrict__ QT, const float* __restrict__ KT,
    const float* __restrict__ V, float* __restrict__ out)
{
    __shared__ __align__(16) float sQ[64][68];  // [k][s-local]
    __shared__ __align__(16) float sK[64][68];  // [k][c]
    __shared__ __align__(16) float sV[64][68];  // [kv][d]
    const int t = threadIdx.x;
    const int bh = blockIdx.x >> 8;
    const int qt = blockIdx.x & 255;
    const int s0 = qt * 64;
    const int rg = t >> 4, cg = t & 15;
    const int laneBase = t & 48;

    #pragma unroll
    for (int i = 0; i < 4; ++i) {
        int f = t + i * 256;
        int k = f >> 4, s4 = f & 15;
        float4 v = *(const float4*)(QT + ((size_t)(bh * 64 + k)) * S_ + s0 + s4 * 4);
        v.x *= 0.125f; v.y *= 0.125f; v.z *= 0.125f; v.w *= 0.125f;
        *(float4*)(&sQ[k][s4 * 4]) = v;
    }

    float ctx[4][4];
    float m_run[4], l_run[4];
    #pragma unroll
    for (int i = 0; i < 4; ++i) {
        m_run[i] = -1e30f; l_run[i] = 0.f;
        #pragma unroll
        for (int j = 0; j < 4; ++j) ctx[i][j] = 0.f;
    }

    for (int ch = 0; ch < 16; ++ch) {
        const int kk0 = ch * 64;
        __syncthreads();
        #pragma unroll
        for (int i = 0; i < 4; ++i) {
            int f = t + i * 256;
            int k = f >> 4, c4 = f & 15;
            *(float4*)(&sK[k][c4 * 4]) =
                *(const float4*)(KT + ((size_t)(bh * 64 + k)) * SK_ + kk0 + c4 * 4);
        }
        #pragma unroll
        for (int i = 0; i < 4; ++i) {
            int f = t + i * 256;
            int r = f >> 4, d4 = f & 15;
            *(float4*)(&sV[r][d4 * 4]) =
                *(const float4*)(V + ((size_t)(bh * SK_ + kk0 + r)) * 64 + d4 * 4);
        }
        __syncthreads();

        // QK^T: rows 4*rg..4*rg+3 (b128), cols 4*cg..4*cg+3 (b128)
        float sc[4][4];
        #pragma unroll
        for (int i = 0; i < 4; ++i)
            #pragma unroll
            for (int j = 0; j < 4; ++j) sc[i][j] = 0.f;
        #pragma unroll 4
        for (int k = 0; k < 64; ++k) {
            float4 qv = *(const float4*)(&sQ[k][rg * 4]);
            float4 kv = *(const float4*)(&sK[k][cg * 4]);
            #pragma unroll
            for (int i = 0; i < 4; ++i) {
                float qi = (&qv.x)[i];
                sc[i][0] += qi * kv.x; sc[i][1] += qi * kv.y;
                sc[i][2] += qi * kv.z; sc[i][3] += qi * kv.w;
            }
        }

        // online softmax, in registers; row-reduce across the 16 cg lanes
        float e[4][4];
        #pragma unroll
        for (int i = 0; i < 4; ++i) {
            float mx = fmaxf(fmaxf(sc[i][0], sc[i][1]), fmaxf(sc[i][2], sc[i][3]));
            mx = fmaxf(mx, __shfl_xor(mx, 1, 64));
            mx = fmaxf(mx, __shfl_xor(mx, 2, 64));
            mx = fmaxf(mx, __shfl_xor(mx, 4, 64));
            mx = fmaxf(mx, __shfl_xor(mx, 8, 64));
            float m_new = fmaxf(m_run[i], mx);
            float fac = __expf(m_run[i] - m_new);
            m_run[i] = m_new;
            float ps = 0.f;
            #pragma unroll
            for (int j = 0; j < 4; ++j) { e[i][j] = __expf(sc[i][j] - m_new); ps += e[i][j]; }
            ps += __shfl_xor(ps, 1, 64);
            ps += __shfl_xor(ps, 2, 64);
            ps += __shfl_xor(ps, 4, 64);
            ps += __shfl_xor(ps, 8, 64);
            l_run[i] = l_run[i] * fac + ps;
            #pragma unroll
            for (int j = 0; j < 4; ++j) ctx[i][j] *= fac;
        }

        // PV: broadcast e across the 16-lane group via shfl
        #pragma unroll 4
        for (int c4 = 0; c4 < 16; ++c4) {
            #pragma unroll
            for (int jj = 0; jj < 4; ++jj) {
                int c = c4 * 4 + jj;
                float4 vv = *(const float4*)(&sV[c][cg * 4]);
                float p[4];
                p[0] = __shfl(e[0][jj], laneBase + c4, 64);
                p[1] = __shfl(e[1][jj], laneBase + c4, 64);
                p[2] = __shfl(e[2][jj], laneBase + c4, 64);
                p[3] = __shfl(e[3][jj], laneBase + c4, 64);
                #pragma unroll
                for (int i = 0; i < 4; ++i) {
                    ctx[i][0] += p[i] * vv.x; ctx[i][1] += p[i] * vv.y;
                    ctx[i][2] += p[i] * vv.z; ctx[i][3] += p[i] * vv.w;
                }
            }
        }
    }

    const int b = bh >> 1, h = bh & 1;
    #pragma unroll
    for (int i = 0; i < 4; ++i) {
        float rl = 1.0f / l_run[i];
        int s = s0 + 4 * rg + i;
        float* dst = out + ((size_t)b * S_ + s) * 128 + h * 64 + cg * 4;
        *(float4*)dst = make_float4(ctx[i][0] * rl, ctx[i][1] * rl,
                                    ctx[i][2] * rl, ctx[i][3] * rl);
    }
}

// ---------------------------------------------------------------- launch
extern "C" void kernel_launch(void* const* d_in, const int* in_sizes, int n_in,
                              void* d_out, int out_size, void* d_ws, size_t ws_size,
                              hipStream_t stream) {
    const float* hid = (const float*)d_in[0];
    const float* fc  = (const float*)d_in[1];
    const float* Wq  = (const float*)d_in[2];
    const float* bq  = (const float*)d_in[3];
    const float* Wk  = (const float*)d_in[4];
    const float* bk  = (const float*)d_in[5];
    const float* Wv  = (const float*)d_in[6];
    const float* bv  = (const float*)d_in[7];
    const float* Wsr = (const float*)d_in[8];
    const float* bsr = (const float*)d_in[9];
    const float* lng = (const float*)d_in[10];
    const float* lnb = (const float*)d_in[11];
    float* out = (float*)d_out;

    float* ws   = (float*)d_ws;
    float* QT   = ws;                 // 4,194,304  [4][64][16384]
    float* KT   = QT + 4194304;       //   262,144  [4][64][1024]
    float* Vv   = KT + 262144;        //   262,144  [4][1024][64]
    float* XR   = Vv + 262144;        //   262,144  [2048][128]
    float* part = XR + 262144;        // 1,048,576  [4][2048][128]
    float* FRK  = part + 1048576;     //    32,768
    float* FIK  = FRK + 32768;        //    32,768
    float* WsrT = FIK + 32768;        //   262,144  [16][128][128]
    float* WqT  = WsrT + 262144;      //    16,384
    float* WkT  = WqT + 16384;        //    16,384
    float* WvT  = WkT + 16384;        //    16,384

    k_transpose128<<<64, 256, 0, stream>>>(Wq, WqT);
    k_transpose128<<<64, 256, 0, stream>>>(Wk, WkT);
    k_transpose128<<<64, 256, 0, stream>>>(Wv, WvT);
    k_wsr_transpose<<<1024, 256, 0, stream>>>(Wsr, WsrT);
    k_freq_avg<<<128, 256, 0, stream>>>(fc, FRK, FIK);

    // Q = hid@Wq^T + bq, RoPE(freqs_cis), write transposed [bh][d][s]
    k_gemm_rope<0, 1><<<1024, 256, 0, stream>>>(hid, WqT, bq, fc, nullptr, QT, S_);
    // conv partials (split-K = 4)
    k_conv<<<256, 256, 0, stream>>>(hid, WsrT, part);
    // LN (reduces partials, adds b_sr)
    k_ln<<<512, 256, 0, stream>>>(part, bsr, lng, lnb, XR);
    // K = XR@Wk^T + bk, RoPE(avg freqs), transposed; V = XR@Wv^T + bv, natural
    k_gemm_rope<1, 1><<<64, 256, 0, stream>>>(XR, WkT, bk, FRK, FIK, KT, SK_);
    k_gemm_rope<2, 0><<<64, 256, 0, stream>>>(XR, WvT, bv, nullptr, nullptr, Vv, SK_);
    // attention
    k_attn<<<1024, 256, 0, stream>>>(QT, KT, Vv, out);
}

// Round 2
// 132.140 us; speedup vs baseline: 3.1711x; 3.1711x over previous
//
#include <hip/hip_runtime.h>
#include <hip/hip_bf16.h>
#include <math.h>

#define B_   2
#define S_   16384
#define C_   128
#define NH_  2
#define SK_  1024
#define IMW_ 128
#define EPS_ 1e-5f

typedef __attribute__((ext_vector_type(8))) short short8v;
typedef __attribute__((ext_vector_type(4))) short short4v;
typedef __attribute__((ext_vector_type(4))) float f32x4;

__device__ __forceinline__ ushort f2bfu(float x) {
    uint u = __float_as_uint(x);
    u += 0x7fffu + ((u >> 16) & 1u);   // RNE
    return (ushort)(u >> 16);
}

// ---------------------------------------------------------------- transposes
__global__ void k_transpose128(const float* __restrict__ W, float* __restrict__ WT) {
    int idx = blockIdx.x * 256 + threadIdx.x;      // 16384
    int k = idx >> 7, j = idx & 127;
    WT[idx] = W[j * 128 + k];                      // WT[k][j] = W[j][k]
}

__global__ void k_wsr_transpose(const float* __restrict__ Wsr, float* __restrict__ WT) {
    int idx = blockIdx.x * 256 + threadIdx.x;      // 262144
    int co  = idx & 127;
    int ci  = (idx >> 7) & 127;
    int tap = idx >> 14;                           // 0..15 = ky*4+kx
    WT[idx] = Wsr[(co * 128 + ci) * 16 + tap];     // WT[tap][ci][co]
}

__global__ void k_freq_avg(const float* __restrict__ fc,
                           float* __restrict__ frk, float* __restrict__ fik) {
    int idx = blockIdx.x * 256 + threadIdx.x;      // 32768 = 1024*32
    int c  = idx & 31;
    int kk = idx >> 5;
    int y = kk >> 5, x = kk & 31;
    float sr = 0.f, si = 0.f;
    #pragma unroll
    for (int i1 = 0; i1 < 4; ++i1)
        #pragma unroll
        for (int i3 = 0; i3 < 4; ++i3) {
            int s = (4 * y + i1) * IMW_ + 4 * x + i3;
            sr += fc[s * 64 + c * 2];
            si += fc[s * 64 + c * 2 + 1];
        }
    frk[idx] = sr * 0.0625f;
    fik[idx] = si * 0.0625f;
}

// ---------------------------------------------------------------- GEMM + RoPE -> bf16
// out = (X @ W^T + bias) [RoPE] * scale, rows = B*SEQP, bf16 output.
// ROPE_MODE: 0 = per-pos interleaved freqs_cis, 1 = frk/fik arrays, 2 = none
// OUTT: 0 -> out[bh][pos][64] ; 1 -> out[bh][dim][SEQP] (transposed)
template<int ROPE_MODE, int OUTT>
__global__ __launch_bounds__(256) void k_gemm_rope(
    const float* __restrict__ X, const float* __restrict__ WT,
    const float* __restrict__ bias, const float* __restrict__ fr,
    const float* __restrict__ fi, ushort* __restrict__ out, int SEQP, float scale)
{
    __shared__ __align__(16) float sX[32][132];
    __shared__ __align__(16) float sW[64][128];
    const int t = threadIdx.x;
    const int row0 = blockIdx.x * 32;
    #pragma unroll
    for (int i = 0; i < 4; ++i) {
        int f = t + i * 256;
        int r = f >> 5, k4 = f & 31;
        *(float4*)(&sX[r][k4 * 4]) =
            *(const float4*)(X + (size_t)(row0 + r) * 128 + k4 * 4);
    }
    const int rg = t >> 4, pg = t & 15;
    const int j0 = pg * 8;
    float acc[2][8];
    #pragma unroll
    for (int i = 0; i < 2; ++i)
        #pragma unroll
        for (int j = 0; j < 8; ++j) acc[i][j] = 0.f;

    for (int half = 0; half < 2; ++half) {
        __syncthreads();
        #pragma unroll
        for (int i = 0; i < 8; ++i) {
            int f = t + i * 256;
            int kk = f >> 5, j4 = f & 31;
            *(float4*)(&sW[kk][j4 * 4]) =
                *(const float4*)(WT + (size_t)(half * 64 + kk) * 128 + j4 * 4);
        }
        __syncthreads();
        #pragma unroll 4
        for (int k4 = 0; k4 < 16; ++k4) {
            float4 hv[2];
            #pragma unroll
            for (int i = 0; i < 2; ++i)
                hv[i] = *(const float4*)(&sX[rg + 16 * i][half * 64 + k4 * 4]);
            #pragma unroll
            for (int kk = 0; kk < 4; ++kk) {
                float4 w0 = *(const float4*)(&sW[k4 * 4 + kk][j0]);
                float4 w1 = *(const float4*)(&sW[k4 * 4 + kk][j0 + 4]);
                #pragma unroll
                for (int i = 0; i < 2; ++i) {
                    float hx = (&hv[i].x)[kk];
                    acc[i][0] += hx * w0.x; acc[i][1] += hx * w0.y;
                    acc[i][2] += hx * w0.z; acc[i][3] += hx * w0.w;
                    acc[i][4] += hx * w1.x; acc[i][5] += hx * w1.y;
                    acc[i][6] += hx * w1.z; acc[i][7] += hx * w1.w;
                }
            }
        }
    }

    const int h  = j0 >> 6;
    const int jl = j0 & 63;
    float bv[8];
    #pragma unroll
    for (int j = 0; j < 8; ++j) bv[j] = bias[j0 + j];
    #pragma unroll
    for (int i = 0; i < 2; ++i) {
        int row = row0 + rg + 16 * i;
        int b   = row / SEQP;
        int pos = row - b * SEQP;
        float o[8];
        if (ROPE_MODE == 2) {
            #pragma unroll
            for (int j = 0; j < 8; ++j) o[j] = acc[i][j] + bv[j];
        } else {
            #pragma unroll
            for (int p = 0; p < 4; ++p) {
                float xr = acc[i][2 * p]     + bv[2 * p];
                float xi = acc[i][2 * p + 1] + bv[2 * p + 1];
                int c = (jl >> 1) + p;
                float frv, fiv;
                if (ROPE_MODE == 0) {
                    frv = fr[(size_t)pos * 64 + c * 2];
                    fiv = fr[(size_t)pos * 64 + c * 2 + 1];
                } else {
                    frv = fr[(size_t)pos * 32 + c];
                    fiv = fi[(size_t)pos * 32 + c];
                }
                o[2 * p]     = xr * frv - xi * fiv;
                o[2 * p + 1] = xr * fiv + xi * frv;
            }
        }
        if (OUTT == 0) {
            uint w0 = (uint)f2bfu(o[0] * scale) | ((uint)f2bfu(o[1] * scale) << 16);
            uint w1 = (uint)f2bfu(o[2] * scale) | ((uint)f2bfu(o[3] * scale) << 16);
            uint w2 = (uint)f2bfu(o[4] * scale) | ((uint)f2bfu(o[5] * scale) << 16);
            uint w3 = (uint)f2bfu(o[6] * scale) | ((uint)f2bfu(o[7] * scale) << 16);
            *(uint4*)(out + ((size_t)(b * NH_ + h) * SEQP + pos) * 64 + jl) =
                make_uint4(w0, w1, w2, w3);
        } else {
            #pragma unroll
            for (int j = 0; j < 8; ++j)
                out[((size_t)(b * NH_ + h) * 64 + jl + j) * SEQP + pos] = f2bfu(o[j] * scale);
        }
    }
}

// ---------------------------------------------------------------- conv (4x4/s4 = patch GEMM), split-K
__global__ __launch_bounds__(256) void k_conv(
    const float* __restrict__ hid, const float* __restrict__ WsrT,
    float* __restrict__ partial)
{
    __shared__ __align__(16) float sA[32][68];
    __shared__ __align__(16) float sB[64][128];
    const int t = threadIdx.x;
    const int split = blockIdx.x >> 6;
    const int by = blockIdx.x & 63;
    const int b = by >> 5, y = by & 31;
    const int rg = t >> 4, pg = t & 15;
    float acc[2][8];
    #pragma unroll
    for (int i = 0; i < 2; ++i)
        #pragma unroll
        for (int j = 0; j < 8; ++j) acc[i][j] = 0.f;

    for (int cc = 0; cc < 8; ++cc) {
        const int tap = split * 4 + (cc >> 1);
        const int ky = tap >> 2, kx = tap & 3;
        const int ci0 = (cc & 1) * 64;
        __syncthreads();
        #pragma unroll
        for (int i = 0; i < 2; ++i) {
            int f = t + i * 256;
            int pos = f >> 4, k4 = f & 15;
            int srow = (4 * y + ky) * IMW_ + 4 * pos + kx;
            *(float4*)(&sA[pos][k4 * 4]) =
                *(const float4*)(hid + ((size_t)b * S_ + srow) * 128 + ci0 + k4 * 4);
        }
        #pragma unroll
        for (int i = 0; i < 8; ++i) {
            int f = t + i * 256;
            int kk = f >> 5, j4 = f & 31;
            *(float4*)(&sB[kk][j4 * 4]) =
                *(const float4*)(WsrT + ((size_t)tap * 128 + ci0 + kk) * 128 + j4 * 4);
        }
        __syncthreads();
        #pragma unroll 4
        for (int kk = 0; kk < 64; ++kk) {
            float a0 = sA[rg][kk], a1 = sA[rg + 16][kk];
            float4 w0 = *(const float4*)(&sB[kk][pg * 8]);
            float4 w1 = *(const float4*)(&sB[kk][pg * 8 + 4]);
            acc[0][0] += a0 * w0.x; acc[0][1] += a0 * w0.y;
            acc[0][2] += a0 * w0.z; acc[0][3] += a0 * w0.w;
            acc[0][4] += a0 * w1.x; acc[0][5] += a0 * w1.y;
            acc[0][6] += a0 * w1.z; acc[0][7] += a0 * w1.w;
            acc[1][0] += a1 * w0.x; acc[1][1] += a1 * w0.y;
            acc[1][2] += a1 * w0.z; acc[1][3] += a1 * w0.w;
            acc[1][4] += a1 * w1.x; acc[1][5] += a1 * w1.y;
            acc[1][6] += a1 * w1.z; acc[1][7] += a1 * w1.w;
        }
    }
    #pragma unroll
    for (int i = 0; i < 2; ++i) {
        int pos = b * SK_ + y * 32 + rg + 16 * i;
        float* dst = partial + ((size_t)split * 2048 + pos) * 128 + pg * 8;
        *(float4*)(dst)     = make_float4(acc[i][0], acc[i][1], acc[i][2], acc[i][3]);
        *(float4*)(dst + 4) = make_float4(acc[i][4], acc[i][5], acc[i][6], acc[i][7]);
    }
}

// ---------------------------------------------------------------- LN (fuses split-K reduce + b_sr)
__global__ __launch_bounds__(256) void k_ln(
    const float* __restrict__ partial, const float* __restrict__ bsr,
    const float* __restrict__ g, const float* __restrict__ bb,
    float* __restrict__ XR)
{
    const int t = threadIdx.x;
    const int row = blockIdx.x * 4 + (t >> 6);
    const int lane = t & 63;
    float x0 = bsr[lane], x1 = bsr[64 + lane];
    #pragma unroll
    for (int s = 0; s < 4; ++s) {
        x0 += partial[((size_t)s * 2048 + row) * 128 + lane];
        x1 += partial[((size_t)s * 2048 + row) * 128 + 64 + lane];
    }
    float sum = x0 + x1;
    #pragma unroll
    for (int m = 1; m < 64; m <<= 1) sum += __shfl_xor(sum, m, 64);
    float mu = sum * (1.0f / 128.0f);
    float d0 = x0 - mu, d1 = x1 - mu;
    float vs = d0 * d0 + d1 * d1;
    #pragma unroll
    for (int m = 1; m < 64; m <<= 1) vs += __shfl_xor(vs, m, 64);
    float rstd = rsqrtf(vs * (1.0f / 128.0f) + EPS_);
    XR[(size_t)row * 128 + lane]      = d0 * rstd * g[lane]      + bb[lane];
    XR[(size_t)row * 128 + 64 + lane] = d1 * rstd * g[64 + lane] + bb[64 + lane];
}

// ---------------------------------------------------------------- flash attention, bf16 MFMA
// Qb: [4][16384][64] bf16 pre-scaled by 0.125*log2e; Kb: [4][1024][64]; VTb: [4][64][1024]
// Block: 256 thr / 4 waves, 128 q-rows; wave w owns q [w*32, w*32+32) = 2 qtiles.
// Swapped QK^T: D[kv][q] so each lane's P column is its own q -> in-register softmax + PV.
__global__ __launch_bounds__(256) void k_attn_mfma(
    const ushort* __restrict__ Qb, const ushort* __restrict__ Kb,
    const ushort* __restrict__ VTb, float* __restrict__ out)
{
    __shared__ ushort sK[64][72];   // [kv][d]  pad 72: uint4-aligned rows, even banks
    __shared__ ushort sVT[64][72];  // [d][kv]
    const int t = threadIdx.x;
    const int lane = t & 63;
    const int w = t >> 6;
    const int g = lane >> 4, ln = lane & 15;
    const int bh = blockIdx.x >> 7;
    const int q0w = (blockIdx.x & 127) * 128 + w * 32;
    const int b = bh >> 1, h = bh & 1;

    // Q fragments (B operand): q = q0w+16qt+ln, d = 32ks+8g+j  (map matches K A-frag)
    short8v qf[2][2];
    #pragma unroll
    for (int qt = 0; qt < 2; ++qt)
        #pragma unroll
        for (int ks = 0; ks < 2; ++ks)
            qf[qt][ks] = *(const short8v*)(
                Qb + ((size_t)bh * S_ + q0w + 16 * qt + ln) * 64 + 32 * ks + 8 * g);

    f32x4 ctx[2][4];
    #pragma unroll
    for (int qt = 0; qt < 2; ++qt)
        #pragma unroll
        for (int dt = 0; dt < 4; ++dt)
            #pragma unroll
            for (int r = 0; r < 4; ++r) ctx[qt][dt][r] = 0.f;
    float m_run[2] = {-3.0e38f, -3.0e38f};
    float l_run[2] = {0.f, 0.f};

    const int sr = t >> 2, scol = (t & 3) * 16;

    for (int ch = 0; ch < 16; ++ch) {
        const int kk0 = ch * 64;
        __syncthreads();
        {
            const ushort* kg = Kb + ((size_t)bh * SK_ + kk0 + sr) * 64 + scol;
            const ushort* vg = VTb + ((size_t)bh * 64 + sr) * SK_ + kk0 + scol;
            uint4 k0 = *(const uint4*)kg;
            uint4 k1 = *(const uint4*)(kg + 8);
            uint4 v0 = *(const uint4*)vg;
            uint4 v1 = *(const uint4*)(vg + 8);
            *(uint4*)&sK[sr][scol]      = k0;
            *(uint4*)&sK[sr][scol + 8]  = k1;
            *(uint4*)&sVT[sr][scol]     = v0;
            *(uint4*)&sVT[sr][scol + 8] = v1;
        }
        __syncthreads();

        // QK^T: sc[kvt][qt], D: row = kv-local (4g+r), col = q-local (ln)
        f32x4 sc[4][2];
        #pragma unroll
        for (int kvt = 0; kvt < 4; ++kvt)
            #pragma unroll
            for (int qt = 0; qt < 2; ++qt)
                #pragma unroll
                for (int r = 0; r < 4; ++r) sc[kvt][qt][r] = 0.f;
        #pragma unroll
        for (int ks = 0; ks < 2; ++ks)
            #pragma unroll
            for (int kvt = 0; kvt < 4; ++kvt) {
                short8v kf = *(const short8v*)&sK[16 * kvt + ln][32 * ks + 8 * g];
                sc[kvt][0] = __builtin_amdgcn_mfma_f32_16x16x32_bf16(kf, qf[0][ks], sc[kvt][0], 0, 0, 0);
                sc[kvt][1] = __builtin_amdgcn_mfma_f32_16x16x32_bf16(kf, qf[1][ks], sc[kvt][1], 0, 0, 0);
            }

        // online softmax in exp2 domain (Q pre-scaled by 0.125*log2e); defer-max THR=8
        #pragma unroll
        for (int qt = 0; qt < 2; ++qt) {
            float mx = sc[0][qt][0];
            #pragma unroll
            for (int kvt = 0; kvt < 4; ++kvt)
                #pragma unroll
                for (int r = 0; r < 4; ++r) mx = fmaxf(mx, sc[kvt][qt][r]);
            mx = fmaxf(mx, __shfl_xor(mx, 16, 64));
            mx = fmaxf(mx, __shfl_xor(mx, 32, 64));
            if (!__all(mx <= m_run[qt] + 8.0f)) {
                float mN  = fmaxf(m_run[qt], mx);
                float fac = __builtin_amdgcn_exp2f(m_run[qt] - mN);
                m_run[qt] = mN;
                l_run[qt] *= fac;
                #pragma unroll
                for (int r = 0; r < 4; ++r) {
                    float fbc = __shfl(fac, 4 * g + r, 64);
                    #pragma unroll
                    for (int dt = 0; dt < 4; ++dt) ctx[qt][dt][r] *= fbc;
                }
            }
            float ps = 0.f;
            #pragma unroll
            for (int kvt = 0; kvt < 4; ++kvt)
                #pragma unroll
                for (int r = 0; r < 4; ++r) {
                    float ev = __builtin_amdgcn_exp2f(sc[kvt][qt][r] - m_run[qt]);
                    sc[kvt][qt][r] = ev;
                    ps += ev;
                }
            ps += __shfl_xor(ps, 16, 64);
            ps += __shfl_xor(ps, 32, 64);
            l_run[qt] += ps;
        }

        // PV: P in registers as A-frag (kv map: j<4 -> 32ks2+4g+j, j>=4 -> +16),
        // V B-frag read with the SAME map from sVT.
        #pragma unroll
        for (int ks2 = 0; ks2 < 2; ++ks2) {
            short8v pf[2];
            #pragma unroll
            for (int qt = 0; qt < 2; ++qt)
                #pragma unroll
                for (int r = 0; r < 4; ++r) {
                    pf[qt][r]     = (short)f2bfu(sc[2 * ks2][qt][r]);
                    pf[qt][4 + r] = (short)f2bfu(sc[2 * ks2 + 1][qt][r]);
                }
            #pragma unroll
            for (int dt = 0; dt < 4; ++dt) {
                const int dd = 16 * dt + ln;
                short4v va = *(const short4v*)&sVT[dd][32 * ks2 + 4 * g];
                short4v vb = *(const short4v*)&sVT[dd][32 * ks2 + 16 + 4 * g];
                short8v vf = __builtin_shufflevector(va, vb, 0, 1, 2, 3, 4, 5, 6, 7);
                ctx[0][dt] = __builtin_amdgcn_mfma_f32_16x16x32_bf16(pf[0], vf, ctx[0][dt], 0, 0, 0);
                ctx[1][dt] = __builtin_amdgcn_mfma_f32_16x16x32_bf16(pf[1], vf, ctx[1][dt], 0, 0, 0);
            }
        }
    }

    #pragma unroll
    for (int qt = 0; qt < 2; ++qt) {
        float inv = 1.0f / l_run[qt];
        #pragma unroll
        for (int r = 0; r < 4; ++r) {
            float ir = __shfl(inv, 4 * g + r, 64);
            int q = q0w + 16 * qt + 4 * g + r;
            float* dst = out + ((size_t)b * S_ + q) * 128 + h * 64;
            #pragma unroll
            for (int dt = 0; dt < 4; ++dt)
                dst[16 * dt + ln] = ctx[qt][dt][r] * ir;
        }
    }
}

// ---------------------------------------------------------------- launch
extern "C" void kernel_launch(void* const* d_in, const int* in_sizes, int n_in,
                              void* d_out, int out_size, void* d_ws, size_t ws_size,
                              hipStream_t stream) {
    const float* hid = (const float*)d_in[0];
    const float* fc  = (const float*)d_in[1];
    const float* Wq  = (const float*)d_in[2];
    const float* bq  = (const float*)d_in[3];
    const float* Wk  = (const float*)d_in[4];
    const float* bk  = (const float*)d_in[5];
    const float* Wv  = (const float*)d_in[6];
    const float* bv  = (const float*)d_in[7];
    const float* Wsr = (const float*)d_in[8];
    const float* bsr = (const float*)d_in[9];
    const float* lng = (const float*)d_in[10];
    const float* lnb = (const float*)d_in[11];
    float* out = (float*)d_out;

    float* ws = (float*)d_ws;
    ushort* Qb  = (ushort*)ws;            // 4*16384*64 bf16 = 2,097,152 float slots
    float* base = ws + 2097152;
    ushort* Kb  = (ushort*)base;          // 262,144 bf16 = 131,072 slots
    ushort* VTb = (ushort*)(base + 131072);
    float* XR   = base + 262144;          //   262,144
    float* part = XR + 262144;            // 1,048,576
    float* FRK  = part + 1048576;         //    32,768
    float* FIK  = FRK + 32768;            //    32,768
    float* WsrT = FIK + 32768;            //   262,144
    float* WqT  = WsrT + 262144;          //    16,384
    float* WkT  = WqT + 16384;            //    16,384
    float* WvT  = WkT + 16384;            //    16,384

    k_transpose128<<<64, 256, 0, stream>>>(Wq, WqT);
    k_transpose128<<<64, 256, 0, stream>>>(Wk, WkT);
    k_transpose128<<<64, 256, 0, stream>>>(Wv, WvT);
    k_wsr_transpose<<<1024, 256, 0, stream>>>(Wsr, WsrT);
    k_freq_avg<<<128, 256, 0, stream>>>(fc, FRK, FIK);

    // Q = RoPE(hid@Wq^T+bq) * (0.125*log2e), bf16 [bh][s][64]
    k_gemm_rope<0, 0><<<1024, 256, 0, stream>>>(hid, WqT, bq, fc, nullptr, Qb, S_,
                                                0.18033688011112042f);
    k_conv<<<256, 256, 0, stream>>>(hid, WsrT, part);
    k_ln<<<512, 256, 0, stream>>>(part, bsr, lng, lnb, XR);
    // K bf16 [bh][1024][64]; V^T bf16 [bh][64][1024]
    k_gemm_rope<1, 0><<<64, 256, 0, stream>>>(XR, WkT, bk, FRK, FIK, Kb, SK_, 1.0f);
    k_gemm_rope<2, 1><<<64, 256, 0, stream>>>(XR, WvT, bv, nullptr, nullptr, VTb, SK_, 1.0f);

    k_attn_mfma<<<512, 256, 0, stream>>>(Qb, Kb, VTb, out);
}

// Round 3
// 98.206 us; speedup vs baseline: 4.2668x; 1.3455x over previous
//
#include <hip/hip_runtime.h>
#include <math.h>

#define B_   2
#define S_   16384
#define C_   128
#define NH_  2
#define SK_  1024
#define IMW_ 128
#define EPS_ 1e-5f

typedef __attribute__((ext_vector_type(8))) short short8v;
typedef __attribute__((ext_vector_type(4))) short short4v;
typedef __attribute__((ext_vector_type(4))) float f32x4;

__device__ __forceinline__ ushort f2bfu(float x) {
    uint u = __float_as_uint(x);
    u += 0x7fffu + ((u >> 16) & 1u);   // RNE
    return (ushort)(u >> 16);
}
__device__ __forceinline__ uint cvtpk(float a, float b) {  // [bf16(a) | bf16(b)<<16]
    uint r;
    asm("v_cvt_pk_bf16_f32 %0, %1, %2" : "=v"(r) : "v"(a), "v"(b));
    return r;
}
__device__ __forceinline__ short8v u4_to_s8(uint4 u) {
    union { uint4 a; short8v b; } c; c.a = u; return c.b;
}

// ---------------------------------------------------------------- fused prep
// blocks: [0,2048) hid->bf16 | [2048,2056) Wq->bf16 | [2056,2184) Wsr->Wsrb
//         [2184,2200) WkT/WvT fp32 transpose | [2200,2328) freq 4x4 mean
__global__ __launch_bounds__(256) void k_prep(
    const float* __restrict__ hid, const float* __restrict__ Wq,
    const float* __restrict__ Wsr, const float* __restrict__ Wk,
    const float* __restrict__ Wv,  const float* __restrict__ fc,
    ushort* __restrict__ hidb, ushort* __restrict__ Wqb, ushort* __restrict__ Wsrb,
    float* __restrict__ WkT, float* __restrict__ WvT,
    float* __restrict__ frk, float* __restrict__ fik)
{
    const int blk = blockIdx.x, t = threadIdx.x;
    if (blk < 2048) {                                  // hid -> bf16
        size_t i = ((size_t)blk * 256 + t) * 8;
        float4 a = *(const float4*)(hid + i);
        float4 b = *(const float4*)(hid + i + 4);
        uint4 o = make_uint4(cvtpk(a.x, a.y), cvtpk(a.z, a.w),
                             cvtpk(b.x, b.y), cvtpk(b.z, b.w));
        *(uint4*)(hidb + i) = o;
    } else if (blk < 2056) {                           // Wq -> bf16 (row-major)
        int i = (blk - 2048) * 2048 + t * 8;
        float4 a = *(const float4*)(Wq + i);
        float4 b = *(const float4*)(Wq + i + 4);
        *(uint4*)(Wqb + i) = make_uint4(cvtpk(a.x, a.y), cvtpk(a.z, a.w),
                                        cvtpk(b.x, b.y), cvtpk(b.z, b.w));
    } else if (blk < 2184) {                           // Wsrb[co][tap*128+ci] <- Wsr[co][ci][tap]
        int i = (blk - 2056) * 2048 + t * 8;
        int co = i >> 11, tap = (i >> 7) & 15, ci = i & 127;
        float v[8];
        #pragma unroll
        for (int j = 0; j < 8; ++j) v[j] = Wsr[((co * 128 + ci + j) * 16) + tap];
        *(uint4*)(Wsrb + i) = make_uint4(cvtpk(v[0], v[1]), cvtpk(v[2], v[3]),
                                         cvtpk(v[4], v[5]), cvtpk(v[6], v[7]));
    } else if (blk < 2200) {                           // WkT / WvT transposes
        int seg = blk - 2184;
        const float* src = (seg < 8) ? Wk : Wv;
        float* dst = (seg < 8) ? WkT : WvT;
        int i = (seg & 7) * 2048 + t * 8;
        int k = i >> 7, j = i & 127;
        float o[8];
        #pragma unroll
        for (int jj = 0; jj < 8; ++jj) o[jj] = src[(j + jj) * 128 + k];
        *(float4*)(dst + i)     = make_float4(o[0], o[1], o[2], o[3]);
        *(float4*)(dst + i + 4) = make_float4(o[4], o[5], o[6], o[7]);
    } else {                                           // freq 4x4 block mean
        int idx = (blk - 2200) * 256 + t;              // 32768 = 1024*32
        int c = idx & 31, kk = idx >> 5;
        int y = kk >> 5, x = kk & 31;
        float sr = 0.f, si = 0.f;
        #pragma unroll
        for (int i1 = 0; i1 < 4; ++i1)
            #pragma unroll
            for (int i3 = 0; i3 < 4; ++i3) {
                int s = (4 * y + i1) * IMW_ + 4 * x + i3;
                sr += fc[s * 64 + c * 2];
                si += fc[s * 64 + c * 2 + 1];
            }
        frk[idx] = sr * 0.0625f;
        fik[idx] = si * 0.0625f;
    }
}

// ---------------------------------------------------------------- Q-GEMM (bf16 MFMA) + RoPE
// out Qb[bh][pos][64] bf16, pre-scaled by 0.125*log2e.
// mfma(A=Wq[c][k], B=X[q][k]) -> D[row=c-local(4g+r)][col=q-local(ln)]:
// RoPE channel pairs land in-lane (consecutive r).
__global__ __launch_bounds__(64) void k_qgemm(
    const ushort* __restrict__ hidb, const ushort* __restrict__ Wqb,
    const float* __restrict__ bq, const float* __restrict__ fc,
    ushort* __restrict__ Qb)
{
    const int lane = threadIdx.x & 63;
    const int g = lane >> 4, ln = lane & 15;
    const int q0 = blockIdx.x * 32;                    // 1024 blocks

    f32x4 acc[2][8];
    #pragma unroll
    for (int qt = 0; qt < 2; ++qt)
        #pragma unroll
        for (int mt = 0; mt < 8; ++mt)
            #pragma unroll
            for (int r = 0; r < 4; ++r) acc[qt][mt][r] = 0.f;

    #pragma unroll
    for (int ks = 0; ks < 4; ++ks) {
        short8v xf[2], wf[8];
        #pragma unroll
        for (int qt = 0; qt < 2; ++qt)
            xf[qt] = *(const short8v*)(hidb + (size_t)(q0 + 16 * qt + ln) * 128 + 32 * ks + 8 * g);
        #pragma unroll
        for (int mt = 0; mt < 8; ++mt)
            wf[mt] = *(const short8v*)(Wqb + (size_t)(16 * mt + ln) * 128 + 32 * ks + 8 * g);
        #pragma unroll
        for (int mt = 0; mt < 8; ++mt) {
            acc[0][mt] = __builtin_amdgcn_mfma_f32_16x16x32_bf16(wf[mt], xf[0], acc[0][mt], 0, 0, 0);
            acc[1][mt] = __builtin_amdgcn_mfma_f32_16x16x32_bf16(wf[mt], xf[1], acc[1][mt], 0, 0, 0);
        }
    }

    const float scale = 0.18033688011112042f;         // 0.125 * log2(e)
    #pragma unroll
    for (int qt = 0; qt < 2; ++qt) {
        int qg = q0 + 16 * qt + ln;                   // [0, 32768)
        int b = qg >> 14, pos = qg & 16383;
        #pragma unroll
        for (int mt = 0; mt < 8; ++mt) {
            int cb = 16 * mt + 4 * g;                 // channel base, %4==0
            float4 fv = *(const float4*)(fc + (size_t)pos * 64 + (cb & 63));
            float4 bv = *(const float4*)(bq + cb);
            float a0 = acc[qt][mt][0] + bv.x;
            float a1 = acc[qt][mt][1] + bv.y;
            float a2 = acc[qt][mt][2] + bv.z;
            float a3 = acc[qt][mt][3] + bv.w;
            float o0 = a0 * fv.x - a1 * fv.y;
            float o1 = a0 * fv.y + a1 * fv.x;
            float o2 = a2 * fv.z - a3 * fv.w;
            float o3 = a2 * fv.w + a3 * fv.z;
            int h = cb >> 6, jl = cb & 63;
            uint2 st = make_uint2(cvtpk(o0 * scale, o1 * scale),
                                  cvtpk(o2 * scale, o3 * scale));
            *(uint2*)(Qb + ((size_t)(b * NH_ + h) * S_ + pos) * 64 + jl) = st;
        }
    }
}

// ---------------------------------------------------------------- conv (bf16 MFMA patch-GEMM)
// XRraw[b][pos][co] fp32 (bias NOT added; added in LN).
__global__ __launch_bounds__(64) void k_convm(
    const ushort* __restrict__ hidb, const ushort* __restrict__ Wsrb,
    float* __restrict__ XRraw)
{
    const int lane = threadIdx.x & 63;
    const int g = lane >> 4, ln = lane & 15;
    const int blk = blockIdx.x;                        // 512 = 2b * 64pt * 4cog
    const int cog = blk & 3;
    const int pt  = (blk >> 2) & 63;
    const int b   = blk >> 8;
    const int y = pt >> 1, x = (pt & 1) * 16 + ln;

    f32x4 acc[2];
    #pragma unroll
    for (int m = 0; m < 2; ++m)
        #pragma unroll
        for (int r = 0; r < 4; ++r) acc[m][r] = 0.f;

    const ushort* hb = hidb + (size_t)b * S_ * 128;
    #pragma unroll 4
    for (int kk = 0; kk < 64; ++kk) {
        int tap = kk >> 2, ci0 = (kk & 3) * 32;
        int ky = tap >> 2, kx = tap & 3;
        short8v xf = *(const short8v*)(hb + ((size_t)((4 * y + ky) * IMW_ + 4 * x + kx)) * 128 + ci0 + 8 * g);
        #pragma unroll
        for (int m = 0; m < 2; ++m) {
            short8v wf = *(const short8v*)(Wsrb + (size_t)(32 * cog + 16 * m + ln) * 2048 + kk * 32 + 8 * g);
            acc[m] = __builtin_amdgcn_mfma_f32_16x16x32_bf16(wf, xf, acc[m], 0, 0, 0);
        }
    }
    const int pos = pt * 16 + ln;
    #pragma unroll
    for (int m = 0; m < 2; ++m) {
        float* dst = XRraw + ((size_t)b * SK_ + pos) * 128 + 32 * cog + 16 * m + 4 * g;
        *(float4*)dst = make_float4(acc[m][0], acc[m][1], acc[m][2], acc[m][3]);
    }
}

// ---------------------------------------------------------------- LN (adds b_sr)
__global__ __launch_bounds__(256) void k_ln(
    const float* __restrict__ XRraw, const float* __restrict__ bsr,
    const float* __restrict__ g, const float* __restrict__ bb,
    float* __restrict__ XR)
{
    const int t = threadIdx.x;
    const int row = blockIdx.x * 4 + (t >> 6);
    const int lane = t & 63;
    float x0 = bsr[lane]      + XRraw[(size_t)row * 128 + lane];
    float x1 = bsr[64 + lane] + XRraw[(size_t)row * 128 + 64 + lane];
    float sum = x0 + x1;
    #pragma unroll
    for (int m = 1; m < 64; m <<= 1) sum += __shfl_xor(sum, m, 64);
    float mu = sum * (1.0f / 128.0f);
    float d0 = x0 - mu, d1 = x1 - mu;
    float vs = d0 * d0 + d1 * d1;
    #pragma unroll
    for (int m = 1; m < 64; m <<= 1) vs += __shfl_xor(vs, m, 64);
    float rstd = rsqrtf(vs * (1.0f / 128.0f) + EPS_);
    XR[(size_t)row * 128 + lane]      = d0 * rstd * g[lane]      + bb[lane];
    XR[(size_t)row * 128 + 64 + lane] = d1 * rstd * g[64 + lane] + bb[64 + lane];
}

// ---------------------------------------------------------------- K/V GEMM (fp32, small) -> bf16
// ROPE_MODE: 1 = frk/fik arrays, 2 = none. OUTT: 0 natural, 1 transposed.
template<int ROPE_MODE, int OUTT>
__global__ __launch_bounds__(256) void k_gemm_rope(
    const float* __restrict__ X, const float* __restrict__ WT,
    const float* __restrict__ bias, const float* __restrict__ fr,
    const float* __restrict__ fi, ushort* __restrict__ out, int SEQP, float scale)
{
    __shared__ __align__(16) float sX[32][132];
    __shared__ __align__(16) float sW[64][128];
    const int t = threadIdx.x;
    const int row0 = blockIdx.x * 32;
    #pragma unroll
    for (int i = 0; i < 4; ++i) {
        int f = t + i * 256;
        int r = f >> 5, k4 = f & 31;
        *(float4*)(&sX[r][k4 * 4]) =
            *(const float4*)(X + (size_t)(row0 + r) * 128 + k4 * 4);
    }
    const int rg = t >> 4, pg = t & 15;
    const int j0 = pg * 8;
    float acc[2][8];
    #pragma unroll
    for (int i = 0; i < 2; ++i)
        #pragma unroll
        for (int j = 0; j < 8; ++j) acc[i][j] = 0.f;

    for (int half = 0; half < 2; ++half) {
        __syncthreads();
        #pragma unroll
        for (int i = 0; i < 8; ++i) {
            int f = t + i * 256;
            int kk = f >> 5, j4 = f & 31;
            *(float4*)(&sW[kk][j4 * 4]) =
                *(const float4*)(WT + (size_t)(half * 64 + kk) * 128 + j4 * 4);
        }
        __syncthreads();
        #pragma unroll 4
        for (int k4 = 0; k4 < 16; ++k4) {
            float4 hv[2];
            #pragma unroll
            for (int i = 0; i < 2; ++i)
                hv[i] = *(const float4*)(&sX[rg + 16 * i][half * 64 + k4 * 4]);
            #pragma unroll
            for (int kk = 0; kk < 4; ++kk) {
                float4 w0 = *(const float4*)(&sW[k4 * 4 + kk][j0]);
                float4 w1 = *(const float4*)(&sW[k4 * 4 + kk][j0 + 4]);
                #pragma unroll
                for (int i = 0; i < 2; ++i) {
                    float hx = (&hv[i].x)[kk];
                    acc[i][0] += hx * w0.x; acc[i][1] += hx * w0.y;
                    acc[i][2] += hx * w0.z; acc[i][3] += hx * w0.w;
                    acc[i][4] += hx * w1.x; acc[i][5] += hx * w1.y;
                    acc[i][6] += hx * w1.z; acc[i][7] += hx * w1.w;
                }
            }
        }
    }

    const int h  = j0 >> 6;
    const int jl = j0 & 63;
    float bv[8];
    #pragma unroll
    for (int j = 0; j < 8; ++j) bv[j] = bias[j0 + j];
    #pragma unroll
    for (int i = 0; i < 2; ++i) {
        int row = row0 + rg + 16 * i;
        int b   = row / SEQP;
        int pos = row - b * SEQP;
        float o[8];
        if (ROPE_MODE == 2) {
            #pragma unroll
            for (int j = 0; j < 8; ++j) o[j] = acc[i][j] + bv[j];
        } else {
            #pragma unroll
            for (int p = 0; p < 4; ++p) {
                float xr = acc[i][2 * p]     + bv[2 * p];
                float xi = acc[i][2 * p + 1] + bv[2 * p + 1];
                int c = (jl >> 1) + p;
                float frv = fr[(size_t)pos * 32 + c];
                float fiv = fi[(size_t)pos * 32 + c];
                o[2 * p]     = xr * frv - xi * fiv;
                o[2 * p + 1] = xr * fiv + xi * frv;
            }
        }
        if (OUTT == 0) {
            uint4 st = make_uint4(cvtpk(o[0] * scale, o[1] * scale),
                                  cvtpk(o[2] * scale, o[3] * scale),
                                  cvtpk(o[4] * scale, o[5] * scale),
                                  cvtpk(o[6] * scale, o[7] * scale));
            *(uint4*)(out + ((size_t)(b * NH_ + h) * SEQP + pos) * 64 + jl) = st;
        } else {
            #pragma unroll
            for (int j = 0; j < 8; ++j)
                out[((size_t)(b * NH_ + h) * 64 + jl + j) * SEQP + pos] = f2bfu(o[j] * scale);
        }
    }
}

// ---------------------------------------------------------------- flash attention, bf16 MFMA
// Qb: [4][16384][64] bf16 (pre-scaled); Kb: [4][1024][64]; VTb: [4][64][1024]
// T14 async stage: next chunk's global loads issued before current compute.
__global__ __launch_bounds__(256) void k_attn_mfma(
    const ushort* __restrict__ Qb, const ushort* __restrict__ Kb,
    const ushort* __restrict__ VTb, float* __restrict__ out)
{
    __shared__ ushort sK[64][72];
    __shared__ ushort sVT[64][72];
    const int t = threadIdx.x;
    const int lane = t & 63;
    const int w = t >> 6;
    const int g = lane >> 4, ln = lane & 15;
    const int bh = blockIdx.x >> 7;
    const int q0w = (blockIdx.x & 127) * 128 + w * 32;
    const int b = bh >> 1, h = bh & 1;

    short8v qf[2][2];
    #pragma unroll
    for (int qt = 0; qt < 2; ++qt)
        #pragma unroll
        for (int ks = 0; ks < 2; ++ks)
            qf[qt][ks] = *(const short8v*)(
                Qb + ((size_t)bh * S_ + q0w + 16 * qt + ln) * 64 + 32 * ks + 8 * g);

    f32x4 ctx[2][4];
    #pragma unroll
    for (int qt = 0; qt < 2; ++qt)
        #pragma unroll
        for (int dt = 0; dt < 4; ++dt)
            #pragma unroll
            for (int r = 0; r < 4; ++r) ctx[qt][dt][r] = 0.f;
    float m_run[2] = {-3.0e38f, -3.0e38f};
    float l_run[2] = {0.f, 0.f};

    const int sr = t >> 2, scol = (t & 3) * 16;
    const ushort* kgBase = Kb  + ((size_t)bh * SK_ + sr) * 64 + scol;
    const ushort* vgBase = VTb + ((size_t)bh * 64 + sr) * SK_ + scol;

    // prologue: chunk 0 straight to LDS
    {
        uint4 k0 = *(const uint4*)(kgBase);
        uint4 k1 = *(const uint4*)(kgBase + 8);
        uint4 v0 = *(const uint4*)(vgBase);
        uint4 v1 = *(const uint4*)(vgBase + 8);
        *(uint4*)&sK[sr][scol]      = k0;
        *(uint4*)&sK[sr][scol + 8]  = k1;
        *(uint4*)&sVT[sr][scol]     = v0;
        *(uint4*)&sVT[sr][scol + 8] = v1;
    }
    __syncthreads();

    uint4 kr0, kr1, vr0, vr1;
    for (int ch = 0; ch < 16; ++ch) {
        if (ch < 15) {   // issue next-chunk loads early (latency hides under compute)
            const ushort* kg = kgBase + (size_t)(ch + 1) * 64 * 64;
            const ushort* vg = vgBase + (ch + 1) * 64;
            kr0 = *(const uint4*)(kg);
            kr1 = *(const uint4*)(kg + 8);
            vr0 = *(const uint4*)(vg);
            vr1 = *(const uint4*)(vg + 8);
        }

        // QK^T (swapped): D rows = kv-local (4g+r), cols = q-local (ln)
        f32x4 sc[4][2];
        #pragma unroll
        for (int kvt = 0; kvt < 4; ++kvt)
            #pragma unroll
            for (int qt = 0; qt < 2; ++qt)
                #pragma unroll
                for (int r = 0; r < 4; ++r) sc[kvt][qt][r] = 0.f;
        #pragma unroll
        for (int ks = 0; ks < 2; ++ks)
            #pragma unroll
            for (int kvt = 0; kvt < 4; ++kvt) {
                short8v kf = *(const short8v*)&sK[16 * kvt + ln][32 * ks + 8 * g];
                sc[kvt][0] = __builtin_amdgcn_mfma_f32_16x16x32_bf16(kf, qf[0][ks], sc[kvt][0], 0, 0, 0);
                sc[kvt][1] = __builtin_amdgcn_mfma_f32_16x16x32_bf16(kf, qf[1][ks], sc[kvt][1], 0, 0, 0);
            }

        // online softmax (exp2 domain), defer-max THR=8
        #pragma unroll
        for (int qt = 0; qt < 2; ++qt) {
            float mx = sc[0][qt][0];
            #pragma unroll
            for (int kvt = 0; kvt < 4; ++kvt)
                #pragma unroll
                for (int r = 0; r < 4; ++r) mx = fmaxf(mx, sc[kvt][qt][r]);
            mx = fmaxf(mx, __shfl_xor(mx, 16, 64));
            mx = fmaxf(mx, __shfl_xor(mx, 32, 64));
            if (!__all(mx <= m_run[qt] + 8.0f)) {
                float mN  = fmaxf(m_run[qt], mx);
                float fac = __builtin_amdgcn_exp2f(m_run[qt] - mN);
                m_run[qt] = mN;
                l_run[qt] *= fac;
                #pragma unroll
                for (int r = 0; r < 4; ++r) {
                    float fbc = __shfl(fac, 4 * g + r, 64);
                    #pragma unroll
                    for (int dt = 0; dt < 4; ++dt) ctx[qt][dt][r] *= fbc;
                }
            }
            float ps = 0.f;
            #pragma unroll
            for (int kvt = 0; kvt < 4; ++kvt)
                #pragma unroll
                for (int r = 0; r < 4; ++r) {
                    float ev = __builtin_amdgcn_exp2f(sc[kvt][qt][r] - m_run[qt]);
                    sc[kvt][qt][r] = ev;
                    ps += ev;
                }
            ps += __shfl_xor(ps, 16, 64);
            ps += __shfl_xor(ps, 32, 64);
            l_run[qt] += ps;
        }

        // PV: P packed in-register via v_cvt_pk_bf16_f32, V read with same k-map
        #pragma unroll
        for (int ks2 = 0; ks2 < 2; ++ks2) {
            union { uint4 u; short8v s; } pf[2];
            #pragma unroll
            for (int qt = 0; qt < 2; ++qt) {
                pf[qt].u.x = cvtpk(sc[2 * ks2][qt][0],     sc[2 * ks2][qt][1]);
                pf[qt].u.y = cvtpk(sc[2 * ks2][qt][2],     sc[2 * ks2][qt][3]);
                pf[qt].u.z = cvtpk(sc[2 * ks2 + 1][qt][0], sc[2 * ks2 + 1][qt][1]);
                pf[qt].u.w = cvtpk(sc[2 * ks2 + 1][qt][2], sc[2 * ks2 + 1][qt][3]);
            }
            #pragma unroll
            for (int dt = 0; dt < 4; ++dt) {
                const int dd = 16 * dt + ln;
                short4v va = *(const short4v*)&sVT[dd][32 * ks2 + 4 * g];
                short4v vb = *(const short4v*)&sVT[dd][32 * ks2 + 16 + 4 * g];
                short8v vf = __builtin_shufflevector(va, vb, 0, 1, 2, 3, 4, 5, 6, 7);
                ctx[0][dt] = __builtin_amdgcn_mfma_f32_16x16x32_bf16(pf[0].s, vf, ctx[0][dt], 0, 0, 0);
                ctx[1][dt] = __builtin_amdgcn_mfma_f32_16x16x32_bf16(pf[1].s, vf, ctx[1][dt], 0, 0, 0);
            }
        }

        __syncthreads();
        if (ch < 15) {   // write prefetched regs -> LDS
            *(uint4*)&sK[sr][scol]      = kr0;
            *(uint4*)&sK[sr][scol + 8]  = kr1;
            *(uint4*)&sVT[sr][scol]     = vr0;
            *(uint4*)&sVT[sr][scol + 8] = vr1;
        }
        __syncthreads();
    }

    #pragma unroll
    for (int qt = 0; qt < 2; ++qt) {
        float inv = 1.0f / l_run[qt];
        #pragma unroll
        for (int r = 0; r < 4; ++r) {
            float ir = __shfl(inv, 4 * g + r, 64);
            int q = q0w + 16 * qt + 4 * g + r;
            float* dst = out + ((size_t)b * S_ + q) * 128 + h * 64;
            #pragma unroll
            for (int dt = 0; dt < 4; ++dt)
                dst[16 * dt + ln] = ctx[qt][dt][r] * ir;
        }
    }
}

// ---------------------------------------------------------------- launch
extern "C" void kernel_launch(void* const* d_in, const int* in_sizes, int n_in,
                              void* d_out, int out_size, void* d_ws, size_t ws_size,
                              hipStream_t stream) {
    const float* hid = (const float*)d_in[0];
    const float* fc  = (const float*)d_in[1];
    const float* Wq  = (const float*)d_in[2];
    const float* bq  = (const float*)d_in[3];
    const float* Wk  = (const float*)d_in[4];
    const float* bk  = (const float*)d_in[5];
    const float* Wv  = (const float*)d_in[6];
    const float* bv  = (const float*)d_in[7];
    const float* Wsr = (const float*)d_in[8];
    const float* bsr = (const float*)d_in[9];
    const float* lng = (const float*)d_in[10];
    const float* lnb = (const float*)d_in[11];
    float* out = (float*)d_out;

    float* ws = (float*)d_ws;
    ushort* Qb   = (ushort*)ws;                  // 2,097,152 fl
    ushort* hidb = (ushort*)(ws + 2097152);      // 2,097,152 fl
    ushort* Kb   = (ushort*)(ws + 4194304);      //   131,072 fl
    ushort* VTb  = (ushort*)(ws + 4325376);      //   131,072 fl
    float*  XR   = ws + 4456448;                 //   262,144
    float*  XRr  = ws + 4718592;                 //   262,144
    float*  FRK  = ws + 4980736;                 //    32,768
    float*  FIK  = ws + 5013504;                 //    32,768
    ushort* Wqb  = (ushort*)(ws + 5046272);      //     8,192 fl
    ushort* Wsrb = (ushort*)(ws + 5054464);      //   131,072 fl
    float*  WkT  = ws + 5185536;                 //    16,384
    float*  WvT  = ws + 5201920;                 //    16,384

    k_prep<<<2328, 256, 0, stream>>>(hid, Wq, Wsr, Wk, Wv, fc,
                                     hidb, Wqb, Wsrb, WkT, WvT, FRK, FIK);
    k_qgemm<<<1024, 64, 0, stream>>>(hidb, Wqb, bq, fc, Qb);
    k_convm<<<512, 64, 0, stream>>>(hidb, Wsrb, XRr);
    k_ln<<<512, 256, 0, stream>>>(XRr, bsr, lng, lnb, XR);
    k_gemm_rope<1, 0><<<64, 256, 0, stream>>>(XR, WkT, bk, FRK, FIK, Kb, SK_, 1.0f);
    k_gemm_rope<2, 1><<<64, 256, 0, stream>>>(XR, WvT, bv, nullptr, nullptr, VTb, SK_, 1.0f);
    k_attn_mfma<<<512, 256, 0, stream>>>(Qb, Kb, VTb, out);
}